// Round 1
// baseline (650.136 us; speedup 1.0000x reference)
//
#include <hip/hip_runtime.h>
#include <stdint.h>

// ---------------------------------------------------------------------------
// AllPairsSimilarity: scores[q] = mean_n max_m ( qhat[q,n] . shat[m] )
// R5:
//  (1) prep_s split into 3 coalesced kernels (old one was ~64-block, 4KB-
//      strided scalar loads => suspected ~280 us hidden cost).
//  (2) fused_gemm spill fix: amdgpu_waves_per_eu(2,2) pins 256-VGPR budget;
//      aF shrunk 40->32 frags (128 VGPR), last 4 k-steps served from LDS Qa
//      (16 slabs x pitch 130 x 16B, quad groups 8 banks apart = 2-way free).
//      Need ~205 regs < 256 => no scratch (WRITE_SIZE 139MB -> ~0).
// Block = 256 thr = 4 waves x 32 n = 128-n strip. Grid = (q=128, ns=8).
// ---------------------------------------------------------------------------

#define NQ   128
#define NP   1024
#define C    640
#define NSH  5
#define EPSN 1e-12f
#define QPITCH 132   // dword pitch of qchunk rows (16B-aligned)
#define QAPITCH 130  // 16B-rows per Qa slab: 130*16B = 2080B -> +8 banks/slab

typedef __attribute__((ext_vector_type(8))) __bf16 bf16x8;
typedef __attribute__((ext_vector_type(4))) float  f32x4;
typedef __attribute__((ext_vector_type(4))) unsigned int u32x4;

__device__ __forceinline__ unsigned short f2bf(float f) {
  unsigned int u = __builtin_bit_cast(unsigned int, f);
  unsigned int r = (u + 0x7fffu + ((u >> 16) & 1u)) >> 16;  // RNE
  return (unsigned short)r;
}

__device__ __forceinline__ void gload16(const void* g, void* l) {
  __builtin_amdgcn_global_load_lds(
      (const __attribute__((address_space(1))) void*)g,
      (__attribute__((address_space(3))) void*)l, 16, 0, 0);
}

// ---------------------------------------------------------------------------
// prep_s, rewritten as 3 small fully-coalesced kernels.
//   zero_ssq : ssq[1024] = 0            (ws is poisoned between iterations)
//   prep_sa  : ssq[m] += sum_c proto[c][m]^2   (grid 4 m-chunks x 20 c-chunks)
//   prep_sb  : Sb[k4][m][8] = bf16(proto * invnorm)  (grid 4 x 80)
// proto recomputed on the fly (S is 13MB, L2-resident) - no extra ws needed.
// ---------------------------------------------------------------------------
__global__ __launch_bounds__(256) void zero_ssq_kernel(float* __restrict__ ssq) {
  ssq[blockIdx.x * 256 + threadIdx.x] = 0.f;
}

__global__ __launch_bounds__(256) void prep_sa_kernel(
    const float* __restrict__ sup, float* __restrict__ ssq) {
  const int t = threadIdx.x;
  const int m = blockIdx.x * 256 + t;      // coalesced across t
  const int c0 = blockIdx.y * 32;
  float ps = 0.f;
  #pragma unroll 4
  for (int c = c0; c < c0 + 32; ++c) {
    float p = 0.f;
    #pragma unroll
    for (int s = 0; s < NSH; ++s) p += sup[((size_t)s * C + c) * NP + m];
    p *= 0.2f;
    ps += p * p;
  }
  atomicAdd(&ssq[m], ps);
}

__global__ __launch_bounds__(256) void prep_sb_kernel(
    const float* __restrict__ sup, const float* __restrict__ ssq,
    unsigned short* __restrict__ Sb) {
  const int t = threadIdx.x;
  const int m = blockIdx.x * 256 + t;      // coalesced across t
  const int k4 = blockIdx.y;               // 0..79
  const int c0 = k4 * 8;
  const float iv = 1.f / fmaxf(sqrtf(ssq[m]), EPSN);
  unsigned int uw[4];
  #pragma unroll
  for (int j = 0; j < 4; ++j) {
    float p0 = 0.f, p1 = 0.f;
    #pragma unroll
    for (int s = 0; s < NSH; ++s) {
      p0 += sup[((size_t)s * C + c0 + 2 * j) * NP + m];
      p1 += sup[((size_t)s * C + c0 + 2 * j + 1) * NP + m];
    }
    p0 *= 0.2f; p1 *= 0.2f;
    uw[j] = (unsigned)f2bf(p0 * iv) | ((unsigned)f2bf(p1 * iv) << 16);
  }
  u32x4 uu = {uw[0], uw[1], uw[2], uw[3]};
  *(u32x4*)&Sb[((size_t)k4 * NP + m) * 8] = uu;
}

// ---------------------------------------------------------------------------
// phase-1 step: stage 64 c-rows of Q (fp32, c-major in LDS), then either
// build 4 A-frags (static reg destinations) or, for the K-tail (CC>=8),
// write the packed frags into LDS Qa[slab][row] for phase-2 reads.
// ---------------------------------------------------------------------------
template <int CC, bool TAIL>
__device__ __forceinline__ void q_step(const float* __restrict__ Qbase,
                                       float* __restrict__ qchunk,
                                       unsigned short* __restrict__ Qa,
                                       f32x4& sq, int nq, int cg, int arow,
                                       int quad,
                                       bf16x8& f00, bf16x8& f01,
                                       bf16x8& f10, bf16x8& f11) {
  #pragma unroll
  for (int i = 0; i < 8; ++i) {
    int c = cg + i * 8;
    f32x4 v = *(const f32x4*)(Qbase + (size_t)(CC * 64 + c) * NP);
    sq += v * v;
    *(f32x4*)&qchunk[c * QPITCH + nq * 4] = v;
  }
  __syncthreads();
  #pragma unroll
  for (int s = 0; s < 2; ++s) {
    #pragma unroll
    for (int nf = 0; nf < 2; ++nf) {
      int row = arow + nf * 16;
      unsigned int uw[4];
      #pragma unroll
      for (int jj = 0; jj < 4; ++jj) {
        int k0 = s * 32 + quad * 8 + jj * 2;
        float v0 = qchunk[k0 * QPITCH + row];
        float v1 = qchunk[(k0 + 1) * QPITCH + row];
        uw[jj] = (unsigned)f2bf(v0) | ((unsigned)f2bf(v1) << 16);
      }
      u32x4 uu = {uw[0], uw[1], uw[2], uw[3]};
      if constexpr (TAIL) {
        // global k-step = CC*2 + s (16..19); slab = (gks-16)*4 + quad
        int slab = (CC - 8) * 8 + s * 4 + quad;  // 0..15
        *(u32x4*)&Qa[(size_t)(slab * QAPITCH + row) * 8] = uu;
      } else {
        bf16x8 r = __builtin_bit_cast(bf16x8, uu);
        if (s == 0 && nf == 0) f00 = r;
        else if (s == 0 && nf == 1) f01 = r;
        else if (s == 1 && nf == 0) f10 = r;
        else f11 = r;
      }
    }
  }
  __syncthreads();
}

// ---------------------------------------------------------------------------
// fused gemm
// ---------------------------------------------------------------------------
__global__ __launch_bounds__(256)
__attribute__((amdgpu_waves_per_eu(2, 2)))
void fused_gemm_kernel(
    const float* __restrict__ Q, const unsigned short* __restrict__ Sb,
    float* __restrict__ partial) {
  // Rg overlay:
  //  phase 1: qchunk f32 [64 c][QPITCH] = 33792 B ; qsums f32 [8][128] @33792
  //  phase 2: Ss bf16 [40 k4][64 m][8]  = 40960 B
  // Qa: bf16 A-frags for k-steps 16..19: 16 slabs x QAPITCH x 16B = 33280 B
  __shared__ __align__(16) char Rg[40960];
  __shared__ __align__(16) unsigned short Qa[16 * QAPITCH * 8];
  __shared__ float invq[128];
  __shared__ float maxbuf[128];
  __shared__ float ssum[2];

  const int t = threadIdx.x;
  const int lane = t & 63, w = t >> 6;
  const int l15 = lane & 15, quad = lane >> 4;
  const int q = blockIdx.x, ns = blockIdx.y;
  const int n0 = ns * 128;

  // ---------------- Phase 1: Q strip (128 n x 640 c) -> aF regs + Qa + invq
  float* qchunk = (float*)Rg;            // [c][QPITCH]
  float* qsums  = (float*)(Rg + 33792);  // [8][128]
  bf16x8 aF[32];                         // k-steps 0..15, STATIC idx only
  bf16x8 dm;                             // dummy sink for TAIL calls
  const int nq = t & 31, cg = t >> 5;
  const float* Qbase = Q + (size_t)q * C * NP + n0 + nq * 4;
  const int arow = w * 32 + l15;
  f32x4 sq = {0.f, 0.f, 0.f, 0.f};

  q_step<0, false>(Qbase, qchunk, Qa, sq, nq, cg, arow, quad, aF[0],  aF[1],  aF[2],  aF[3]);
  q_step<1, false>(Qbase, qchunk, Qa, sq, nq, cg, arow, quad, aF[4],  aF[5],  aF[6],  aF[7]);
  q_step<2, false>(Qbase, qchunk, Qa, sq, nq, cg, arow, quad, aF[8],  aF[9],  aF[10], aF[11]);
  q_step<3, false>(Qbase, qchunk, Qa, sq, nq, cg, arow, quad, aF[12], aF[13], aF[14], aF[15]);
  q_step<4, false>(Qbase, qchunk, Qa, sq, nq, cg, arow, quad, aF[16], aF[17], aF[18], aF[19]);
  q_step<5, false>(Qbase, qchunk, Qa, sq, nq, cg, arow, quad, aF[20], aF[21], aF[22], aF[23]);
  q_step<6, false>(Qbase, qchunk, Qa, sq, nq, cg, arow, quad, aF[24], aF[25], aF[26], aF[27]);
  q_step<7, false>(Qbase, qchunk, Qa, sq, nq, cg, arow, quad, aF[28], aF[29], aF[30], aF[31]);
  q_step<8, true >(Qbase, qchunk, Qa, sq, nq, cg, arow, quad, dm, dm, dm, dm);
  q_step<9, true >(Qbase, qchunk, Qa, sq, nq, cg, arow, quad, dm, dm, dm, dm);

  #pragma unroll
  for (int j = 0; j < 4; ++j) qsums[cg * 128 + nq * 4 + j] = sq[j];
  __syncthreads();
  if (t < 128) {
    float s = 0.f;
    #pragma unroll
    for (int g = 0; g < 8; ++g) s += qsums[g * 128 + t];
    invq[t] = 1.f / fmaxf(sqrtf(s), EPSN);
  }
  __syncthreads();

  // ---------------- Phase 2: stream 16 m-tiles of 64 ----------------------
  unsigned short* Ss = (unsigned short*)Rg;  // [40 k4][64 m][8]
  f32x4 ninf = {-3.0e38f, -3.0e38f, -3.0e38f, -3.0e38f};
  f32x4 rm[2] = {ninf, ninf};

  for (int mt = 0; mt < 16; ++mt) {
    f32x4 zero = {0.f, 0.f, 0.f, 0.f};
    f32x4 acc[2][4];
    #pragma unroll
    for (int nf = 0; nf < 2; ++nf)
      #pragma unroll
      for (int mf = 0; mf < 4; ++mf) acc[nf][mf] = zero;

    #pragma unroll
    for (int h = 0; h < 2; ++h) {
      // stage 64 m x 320 k (k4 = h*40 + it*4 + w), fully coalesced
      const unsigned short* gsrc =
          Sb + ((size_t)(h * 40 + w) * 1024 + mt * 64 + lane) * 8;
      #pragma unroll
      for (int it = 0; it < 10; ++it)
        gload16(gsrc + (size_t)it * 32768, (char*)Ss + (it * 256 + t) * 16);
      __syncthreads();
      #pragma unroll
      for (int ks = 0; ks < 10; ++ks) {
        const int gks = h * 10 + ks;     // 0..19, literal after unroll
        bf16x8 a0, a1;
        if (gks < 16) {
          a0 = aF[(gks & 15) * 2 + 0];
          a1 = aF[(gks & 15) * 2 + 1];
        } else {
          const int slab = ((gks - 16) & 3) * 4 + quad;
          a0 = *(const bf16x8*)&Qa[(size_t)(slab * QAPITCH + arow) * 8];
          a1 = *(const bf16x8*)&Qa[(size_t)(slab * QAPITCH + arow + 16) * 8];
        }
        #pragma unroll
        for (int mf = 0; mf < 4; ++mf) {
          bf16x8 b = *(const bf16x8*)((char*)Ss +
              (size_t)(((ks * 4 + quad) * 64) + mf * 16 + l15) * 16);
          acc[0][mf] = __builtin_amdgcn_mfma_f32_16x16x32_bf16(
              a0, b, acc[0][mf], 0, 0, 0);
          acc[1][mf] = __builtin_amdgcn_mfma_f32_16x16x32_bf16(
              a1, b, acc[1][mf], 0, 0, 0);
        }
      }
      __syncthreads();
    }
    // fold m-tile into running max
    #pragma unroll
    for (int nf = 0; nf < 2; ++nf)
      #pragma unroll
      for (int r = 0; r < 4; ++r) {
        float mv = fmaxf(fmaxf(acc[nf][0][r], acc[nf][1][r]),
                         fmaxf(acc[nf][2][r], acc[nf][3][r]));
        rm[nf][r] = fmaxf(rm[nf][r], mv);
      }
  }

  // ---------------- Epilogue ----------------------------------------------
  #pragma unroll
  for (int off = 8; off >= 1; off >>= 1)
    #pragma unroll
    for (int nf = 0; nf < 2; ++nf)
      #pragma unroll
      for (int r = 0; r < 4; ++r)
        rm[nf][r] = fmaxf(rm[nf][r], __shfl_xor(rm[nf][r], off, 64));
  if (l15 == 0) {
    #pragma unroll
    for (int nf = 0; nf < 2; ++nf)
      #pragma unroll
      for (int r = 0; r < 4; ++r)
        maxbuf[w * 32 + nf * 16 + quad * 4 + r] = rm[nf][r];
  }
  __syncthreads();
  if (t < 128) {
    float v = maxbuf[t] * invq[t];
    #pragma unroll
    for (int off = 32; off >= 1; off >>= 1) v += __shfl_down(v, off, 64);
    if (lane == 0) ssum[w] = v;
  }
  __syncthreads();
  if (t == 0)
    partial[q * 8 + ns] = (ssum[0] + ssum[1]) * (1.f / 1024.f);
}

__global__ void reduce_out_kernel(const float* __restrict__ partial,
                                  float* __restrict__ out) {
  int t = threadIdx.x;  // 128
  float s = 0.f;
  #pragma unroll
  for (int i = 0; i < 8; ++i) s += partial[t * 8 + i];
  out[t] = s;
}

// ---------------------------------------------------------------------------
extern "C" void kernel_launch(void* const* d_in, const int* in_sizes, int n_in,
                              void* d_out, int out_size, void* d_ws, size_t ws_size,
                              hipStream_t stream) {
  const float* Q = (const float*)d_in[0];
  const float* S = (const float*)d_in[1];
  char* ws = (char*)d_ws;

  // ws: Sb bf16 k-major [80][1024][8] = 1,310,720 B
  //     partial f32 [128][8]          @ 1,310,720
  //     ssq     f32 [1024]            @ 1,314,816   (total 1,318,912 B)
  unsigned short* Sb   = (unsigned short*)ws;
  float*          part = (float*)(ws + 1310720ull);
  float*          ssq  = (float*)(ws + 1314816ull);
  float*          out  = (float*)d_out;

  zero_ssq_kernel<<<4, 256, 0, stream>>>(ssq);
  prep_sa_kernel<<<dim3(4, 20), 256, 0, stream>>>(S, ssq);
  prep_sb_kernel<<<dim3(4, 80), 256, 0, stream>>>(S, ssq, Sb);
  fused_gemm_kernel<<<dim3(128, 8), 256, 0, stream>>>(Q, Sb, part);
  reduce_out_kernel<<<1, 128, 0, stream>>>(part, out);
}

// Round 2
// 610.320 us; speedup vs baseline: 1.0652x; 1.0652x over previous
//
#include <hip/hip_runtime.h>
#include <stdint.h>

// ---------------------------------------------------------------------------
// AllPairsSimilarity: scores[q] = mean_n max_m ( qhat[q,n] . shat[m] )
// R6: back to R4 structure (all 20 k-steps register-resident, no Qa LDS path)
// with two anti-spill measures:
//   (a) amdgpu_num_vgpr(256) + amdgpu_waves_per_eu(2,2): force the 256-reg
//       budget (2 waves/EU). R4/R5 were silently capped at 128 -> 62-139MB
//       scratch traffic.
//   (b) aF de-arrayified into 40 NAMED bf16x8 variables (macro-expanded
//       phase-2) so SROA cannot fall back to a stack array.
// prep chain kept from R5 (3 tiny coalesced kernels).
// Block = 256 thr = 4 waves x 32 n = 128-n strip. Grid = (q=128, ns=8).
// ---------------------------------------------------------------------------

#define NQ   128
#define NP   1024
#define C    640
#define NSH  5
#define EPSN 1e-12f
#define QPITCH 132   // dword pitch of qchunk rows (16B-aligned)

typedef __attribute__((ext_vector_type(8))) __bf16 bf16x8;
typedef __attribute__((ext_vector_type(4))) float  f32x4;
typedef __attribute__((ext_vector_type(4))) unsigned int u32x4;

__device__ __forceinline__ unsigned short f2bf(float f) {
  unsigned int u = __builtin_bit_cast(unsigned int, f);
  unsigned int r = (u + 0x7fffu + ((u >> 16) & 1u)) >> 16;  // RNE
  return (unsigned short)r;
}

__device__ __forceinline__ void gload16(const void* g, void* l) {
  __builtin_amdgcn_global_load_lds(
      (const __attribute__((address_space(1))) void*)g,
      (__attribute__((address_space(3))) void*)l, 16, 0, 0);
}

// ---------------------------------------------------------------------------
// prep chain (3 tiny coalesced kernels, from R5)
// ---------------------------------------------------------------------------
__global__ __launch_bounds__(256) void zero_ssq_kernel(float* __restrict__ ssq) {
  ssq[blockIdx.x * 256 + threadIdx.x] = 0.f;
}

__global__ __launch_bounds__(256) void prep_sa_kernel(
    const float* __restrict__ sup, float* __restrict__ ssq) {
  const int t = threadIdx.x;
  const int m = blockIdx.x * 256 + t;      // coalesced across t
  const int c0 = blockIdx.y * 32;
  float ps = 0.f;
  #pragma unroll 4
  for (int c = c0; c < c0 + 32; ++c) {
    float p = 0.f;
    #pragma unroll
    for (int s = 0; s < NSH; ++s) p += sup[((size_t)s * C + c) * NP + m];
    p *= 0.2f;
    ps += p * p;
  }
  atomicAdd(&ssq[m], ps);
}

__global__ __launch_bounds__(256) void prep_sb_kernel(
    const float* __restrict__ sup, const float* __restrict__ ssq,
    unsigned short* __restrict__ Sb) {
  const int t = threadIdx.x;
  const int m = blockIdx.x * 256 + t;      // coalesced across t
  const int k4 = blockIdx.y;               // 0..79
  const int c0 = k4 * 8;
  const float iv = 1.f / fmaxf(sqrtf(ssq[m]), EPSN);
  unsigned int uw[4];
  #pragma unroll
  for (int j = 0; j < 4; ++j) {
    float p0 = 0.f, p1 = 0.f;
    #pragma unroll
    for (int s = 0; s < NSH; ++s) {
      p0 += sup[((size_t)s * C + c0 + 2 * j) * NP + m];
      p1 += sup[((size_t)s * C + c0 + 2 * j + 1) * NP + m];
    }
    p0 *= 0.2f; p1 *= 0.2f;
    uw[j] = (unsigned)f2bf(p0 * iv) | ((unsigned)f2bf(p1 * iv) << 16);
  }
  u32x4 uu = {uw[0], uw[1], uw[2], uw[3]};
  *(u32x4*)&Sb[((size_t)k4 * NP + m) * 8] = uu;
}

// ---------------------------------------------------------------------------
// phase-1 step: stage 64 c-rows of Q (fp32, c-major in LDS), build the 4
// A-frags for k-steps 2*CC and 2*CC+1 with compile-time destinations.
// ---------------------------------------------------------------------------
template <int CC>
__device__ __forceinline__ void q_step(const float* __restrict__ Qbase,
                                       float* __restrict__ qchunk,
                                       f32x4& sq, int nq, int cg, int arow,
                                       int quad,
                                       bf16x8& f00, bf16x8& f01,
                                       bf16x8& f10, bf16x8& f11) {
  #pragma unroll
  for (int i = 0; i < 8; ++i) {
    int c = cg + i * 8;
    f32x4 v = *(const f32x4*)(Qbase + (size_t)(CC * 64 + c) * NP);
    sq += v * v;
    *(f32x4*)&qchunk[c * QPITCH + nq * 4] = v;
  }
  __syncthreads();
  #pragma unroll
  for (int s = 0; s < 2; ++s) {
    #pragma unroll
    for (int nf = 0; nf < 2; ++nf) {
      int row = arow + nf * 16;
      unsigned int uw[4];
      #pragma unroll
      for (int jj = 0; jj < 4; ++jj) {
        int k0 = s * 32 + quad * 8 + jj * 2;
        float v0 = qchunk[k0 * QPITCH + row];
        float v1 = qchunk[(k0 + 1) * QPITCH + row];
        uw[jj] = (unsigned)f2bf(v0) | ((unsigned)f2bf(v1) << 16);
      }
      u32x4 uu = {uw[0], uw[1], uw[2], uw[3]};
      bf16x8 r = __builtin_bit_cast(bf16x8, uu);
      if (s == 0 && nf == 0) f00 = r;
      else if (s == 0 && nf == 1) f01 = r;
      else if (s == 1 && nf == 0) f10 = r;
      else f11 = r;
    }
  }
  __syncthreads();
}

// one k-step of phase 2: 4 B-frag loads, 8 MFMAs, frag names pasted in
#define KSTEP(KS, A0, A1)                                                   \
  do {                                                                      \
    _Pragma("unroll")                                                       \
    for (int mf = 0; mf < 4; ++mf) {                                        \
      bf16x8 b = *(const bf16x8*)((char*)Ss +                               \
          (size_t)((((KS) * 4 + quad) * 64) + mf * 16 + l15) * 16);         \
      acc[0][mf] = __builtin_amdgcn_mfma_f32_16x16x32_bf16(                 \
          A0, b, acc[0][mf], 0, 0, 0);                                      \
      acc[1][mf] = __builtin_amdgcn_mfma_f32_16x16x32_bf16(                 \
          A1, b, acc[1][mf], 0, 0, 0);                                      \
    }                                                                       \
  } while (0)

// ---------------------------------------------------------------------------
// fused gemm
// ---------------------------------------------------------------------------
__global__ __launch_bounds__(256)
__attribute__((amdgpu_waves_per_eu(2, 2), amdgpu_num_vgpr(256)))
void fused_gemm_kernel(
    const float* __restrict__ Q, const unsigned short* __restrict__ Sb,
    float* __restrict__ partial) {
  // Rg overlay:
  //  phase 1: qchunk f32 [64 c][QPITCH] = 33792 B ; qsums f32 [8][128] @33792
  //  phase 2: Ss bf16 [40 k4][64 m][8]  = 40960 B
  __shared__ __align__(16) char Rg[40960];
  __shared__ float invq[128];
  __shared__ float maxbuf[128];
  __shared__ float ssum[2];

  const int t = threadIdx.x;
  const int lane = t & 63, w = t >> 6;
  const int l15 = lane & 15, quad = lane >> 4;
  const int q = blockIdx.x, ns = blockIdx.y;
  const int n0 = ns * 128;

  // ---------------- Phase 1: Q strip (128 n x 640 c) -> named frags + invq
  float* qchunk = (float*)Rg;            // [c][QPITCH]
  float* qsums  = (float*)(Rg + 33792);  // [8][128]
  // 40 NAMED frags: aS<step><slot>, step=0..9 covers k-steps {2s, 2s+1},
  // slot: 0=(k even,nf0) 1=(k even,nf1) 2=(k odd,nf0) 3=(k odd,nf1)
  bf16x8 a00, a01, a02, a03, a10, a11, a12, a13;
  bf16x8 a20, a21, a22, a23, a30, a31, a32, a33;
  bf16x8 a40, a41, a42, a43, a50, a51, a52, a53;
  bf16x8 a60, a61, a62, a63, a70, a71, a72, a73;
  bf16x8 a80, a81, a82, a83, a90, a91, a92, a93;
  const int nq = t & 31, cg = t >> 5;
  const float* Qbase = Q + (size_t)q * C * NP + n0 + nq * 4;
  const int arow = w * 32 + l15;
  f32x4 sq = {0.f, 0.f, 0.f, 0.f};

  q_step<0>(Qbase, qchunk, sq, nq, cg, arow, quad, a00, a01, a02, a03);
  q_step<1>(Qbase, qchunk, sq, nq, cg, arow, quad, a10, a11, a12, a13);
  q_step<2>(Qbase, qchunk, sq, nq, cg, arow, quad, a20, a21, a22, a23);
  q_step<3>(Qbase, qchunk, sq, nq, cg, arow, quad, a30, a31, a32, a33);
  q_step<4>(Qbase, qchunk, sq, nq, cg, arow, quad, a40, a41, a42, a43);
  q_step<5>(Qbase, qchunk, sq, nq, cg, arow, quad, a50, a51, a52, a53);
  q_step<6>(Qbase, qchunk, sq, nq, cg, arow, quad, a60, a61, a62, a63);
  q_step<7>(Qbase, qchunk, sq, nq, cg, arow, quad, a70, a71, a72, a73);
  q_step<8>(Qbase, qchunk, sq, nq, cg, arow, quad, a80, a81, a82, a83);
  q_step<9>(Qbase, qchunk, sq, nq, cg, arow, quad, a90, a91, a92, a93);

  #pragma unroll
  for (int j = 0; j < 4; ++j) qsums[cg * 128 + nq * 4 + j] = sq[j];
  __syncthreads();
  if (t < 128) {
    float s = 0.f;
    #pragma unroll
    for (int g = 0; g < 8; ++g) s += qsums[g * 128 + t];
    invq[t] = 1.f / fmaxf(sqrtf(s), EPSN);
  }
  __syncthreads();

  // ---------------- Phase 2: stream 16 m-tiles of 64 ----------------------
  unsigned short* Ss = (unsigned short*)Rg;  // [40 k4][64 m][8]
  f32x4 ninf = {-3.0e38f, -3.0e38f, -3.0e38f, -3.0e38f};
  f32x4 rm[2] = {ninf, ninf};

  for (int mt = 0; mt < 16; ++mt) {
    f32x4 zero = {0.f, 0.f, 0.f, 0.f};
    f32x4 acc[2][4];
    #pragma unroll
    for (int nf = 0; nf < 2; ++nf)
      #pragma unroll
      for (int mf = 0; mf < 4; ++mf) acc[nf][mf] = zero;

    // ---- h = 0: k-steps 0..9 (steps 0..4) ----
    {
      const unsigned short* gsrc =
          Sb + ((size_t)(0 * 40 + w) * 1024 + mt * 64 + lane) * 8;
      #pragma unroll
      for (int it = 0; it < 10; ++it)
        gload16(gsrc + (size_t)it * 32768, (char*)Rg + (it * 256 + t) * 16);
      __syncthreads();
      KSTEP(0, a00, a01); KSTEP(1, a02, a03);
      KSTEP(2, a10, a11); KSTEP(3, a12, a13);
      KSTEP(4, a20, a21); KSTEP(5, a22, a23);
      KSTEP(6, a30, a31); KSTEP(7, a32, a33);
      KSTEP(8, a40, a41); KSTEP(9, a42, a43);
      __syncthreads();
    }
    // ---- h = 1: k-steps 10..19 (steps 5..9) ----
    {
      const unsigned short* gsrc =
          Sb + ((size_t)(1 * 40 + w) * 1024 + mt * 64 + lane) * 8;
      #pragma unroll
      for (int it = 0; it < 10; ++it)
        gload16(gsrc + (size_t)it * 32768, (char*)Rg + (it * 256 + t) * 16);
      __syncthreads();
      KSTEP(0, a50, a51); KSTEP(1, a52, a53);
      KSTEP(2, a60, a61); KSTEP(3, a62, a63);
      KSTEP(4, a70, a71); KSTEP(5, a72, a73);
      KSTEP(6, a80, a81); KSTEP(7, a82, a83);
      KSTEP(8, a90, a91); KSTEP(9, a92, a93);
      __syncthreads();
    }
    // fold m-tile into running max
    #pragma unroll
    for (int nf = 0; nf < 2; ++nf)
      #pragma unroll
      for (int r = 0; r < 4; ++r) {
        float mv = fmaxf(fmaxf(acc[nf][0][r], acc[nf][1][r]),
                         fmaxf(acc[nf][2][r], acc[nf][3][r]));
        rm[nf][r] = fmaxf(rm[nf][r], mv);
      }
  }

  // ---------------- Epilogue ----------------------------------------------
  #pragma unroll
  for (int off = 8; off >= 1; off >>= 1)
    #pragma unroll
    for (int nf = 0; nf < 2; ++nf)
      #pragma unroll
      for (int r = 0; r < 4; ++r)
        rm[nf][r] = fmaxf(rm[nf][r], __shfl_xor(rm[nf][r], off, 64));
  if (l15 == 0) {
    #pragma unroll
    for (int nf = 0; nf < 2; ++nf)
      #pragma unroll
      for (int r = 0; r < 4; ++r)
        maxbuf[w * 32 + nf * 16 + quad * 4 + r] = rm[nf][r];
  }
  __syncthreads();
  if (t < 128) {
    float v = maxbuf[t] * invq[t];
    #pragma unroll
    for (int off = 32; off >= 1; off >>= 1) v += __shfl_down(v, off, 64);
    if (lane == 0) ssum[w] = v;
  }
  __syncthreads();
  if (t == 0)
    partial[q * 8 + ns] = (ssum[0] + ssum[1]) * (1.f / 1024.f);
}

__global__ void reduce_out_kernel(const float* __restrict__ partial,
                                  float* __restrict__ out) {
  int t = threadIdx.x;  // 128
  float s = 0.f;
  #pragma unroll
  for (int i = 0; i < 8; ++i) s += partial[t * 8 + i];
  out[t] = s;
}

// ---------------------------------------------------------------------------
extern "C" void kernel_launch(void* const* d_in, const int* in_sizes, int n_in,
                              void* d_out, int out_size, void* d_ws, size_t ws_size,
                              hipStream_t stream) {
  const float* Q = (const float*)d_in[0];
  const float* S = (const float*)d_in[1];
  char* ws = (char*)d_ws;

  // ws: Sb bf16 k-major [80][1024][8] = 1,310,720 B
  //     partial f32 [128][8]          @ 1,310,720
  //     ssq     f32 [1024]            @ 1,314,816   (total 1,318,912 B)
  unsigned short* Sb   = (unsigned short*)ws;
  float*          part = (float*)(ws + 1310720ull);
  float*          ssq  = (float*)(ws + 1314816ull);
  float*          out  = (float*)d_out;

  zero_ssq_kernel<<<4, 256, 0, stream>>>(ssq);
  prep_sa_kernel<<<dim3(4, 20), 256, 0, stream>>>(S, ssq);
  prep_sb_kernel<<<dim3(4, 80), 256, 0, stream>>>(S, ssq, Sb);
  fused_gemm_kernel<<<dim3(128, 8), 256, 0, stream>>>(Q, Sb, part);
  reduce_out_kernel<<<1, 128, 0, stream>>>(part, out);
}